// Round 1
// baseline (949.236 us; speedup 1.0000x reference)
//
#include <hip/hip_runtime.h>

namespace {
constexpr int D_  = 4;
constexpr int ND  = 9;     // 2D+1
constexpr int NK  = 81;
constexpr int B_  = 4, C_ = 64, H_ = 192, W_ = 448;

constexpr int NG  = 3;     // dy-groups (encoded fastest-varying in blockIdx.x)
constexpr int GD  = 3;     // dy values per block  (NG*GD == ND)

constexpr int TH  = 16;    // output rows per block
constexpr int TXN = 16;    // threads along x
constexpr int PX  = 4;     // pixels per thread along x
constexpr int TW  = TXN * PX;          // 64
constexpr int CCH = 4;                 // channels staged per round
constexpr int NR  = TH + GD - 1;       // 18 staged rows (dy halo)
constexpr int HC  = TW + 2 * D_;       // 72 halo cols
constexpr int HCP = 76;                // padded LDS row stride (76%32=12 -> b128 conflict-free)
constexpr int NTH = TH * TXN;          // 256
constexpr int F4R = HC / 4;            // 18 float4 per staged row
constexpr int STG = CCH * NR * F4R;    // 1296 float4 per round
constexpr int SIT = (STG + NTH - 1) / NTH;   // 6 staging iters (last partial)
constexpr int ROUNDS = C_ / CCH;       // 16
constexpr int BUFSZ  = CCH * NR * HCP; // 5472 floats = 21888 B per buffer
constexpr int PLANE  = H_ * W_;        // 86016
}

__global__ __launch_bounds__(NTH, 2)
void corr81_kernel(const float* __restrict__ f1, const float* __restrict__ f2,
                   float* __restrict__ out)
{
    __shared__ float s2[2][BUFSZ];     // double-buffered: 43776 B total

    const int tid = threadIdx.x;
    const int tx  = tid & (TXN - 1);
    const int ty  = tid >> 4;

    const int bx    = blockIdx.x;
    const int tilex = bx / NG;
    const int g     = bx - tilex * NG; // dy-group 0..2, fastest-varying -> L3 temporal locality

    const int x0 = tilex * TW;
    const int y0 = blockIdx.y * TH;
    const int b  = blockIdx.z;

    const int gx = x0 + tx * PX;
    const int gy = y0 + ty;
    const int yb = y0 + g * GD - D_;   // first staged feat2 row

    float acc[GD][ND][PX];
#pragma unroll
    for (int s = 0; s < GD; ++s)
#pragma unroll
        for (int dx = 0; dx < ND; ++dx)
#pragma unroll
            for (int p = 0; p < PX; ++p) acc[s][dx][p] = 0.f;

    // ---- precompute staging geometry (round-invariant) ----
    int  gidx[SIT];    // feat2 element index at cc=0 (clamped; guarded by ld[])
    int  lofs[SIT];    // LDS float offset within one buffer
    bool ld[SIT];      // global load is in-bounds
    bool wr[SIT];      // lds write active (l < STG)
#pragma unroll
    for (int i = 0; i < SIT; ++i) {
        int l   = tid + NTH * i;
        int c   = l / (NR * F4R);
        int rem = l - c * (NR * F4R);
        int r   = rem / F4R;
        int p   = rem - r * F4R;
        int yy  = yb + r;
        int xx  = x0 - D_ + 4 * p;
        wr[i]   = (l < STG);
        ld[i]   = wr[i] && (yy >= 0) && (yy < H_) && (xx >= 0) && (xx < W_);
        int yc  = yy < 0 ? 0 : (yy >= H_ ? H_ - 1 : yy);
        int xc  = xx < 0 ? 0 : (xx >= W_ ? W_ - 4 : xx);
        lofs[i] = (c * NR + r) * HCP + 4 * p;
        gidx[i] = ((b * C_ + c) * H_ + yc) * W_ + xc;
    }

    // ---- stage round 0 into buffer 0 ----
    float4 v[SIT];
#pragma unroll
    for (int i = 0; i < SIT; ++i) {
        float4 t = make_float4(0.f, 0.f, 0.f, 0.f);
        if (ld[i]) t = *(const float4*)(f2 + gidx[i]);
        v[i] = t;
    }
#pragma unroll
    for (int i = 0; i < SIT; ++i)
        if (wr[i]) *(float4*)&s2[0][lofs[i]] = v[i];

    const float* f1q = f1 + ((size_t)(b * C_) * H_ + gy) * W_ + gx;
    float* const opb = out + ((size_t)(b * NK) * H_ + gy) * W_ + gx;

#pragma unroll 2
    for (int rr = 0; rr < ROUNDS; ++rr) {
        const int cur = rr & 1;
        __syncthreads();   // staged data in s2[cur] visible; prior reads of s2[cur^1] done

        // ---- prefetch next round: issue loads early (overlap with compute) ----
        if (rr + 1 < ROUNDS) {
            const int cof = (rr + 1) * CCH * PLANE;
#pragma unroll
            for (int i = 0; i < SIT; ++i) {
                float4 t = make_float4(0.f, 0.f, 0.f, 0.f);
                if (ld[i]) t = *(const float4*)(f2 + gidx[i] + cof);
                v[i] = t;
            }
        }

        // ---- compute current round from s2[cur] ----
        const float* sb = &s2[cur][0];
#pragma unroll
        for (int c = 0; c < CCH; ++c) {
            float4 af = *(const float4*)(f1q + (size_t)(rr * CCH + c) * PLANE);
            float a_[PX] = {af.x, af.y, af.z, af.w};
#pragma unroll
            for (int s = 0; s < GD; ++s) {
                const float* rp = sb + (c * NR + ty + s) * HCP + 4 * tx;
                float r_[12];
                *(float4*)&r_[0] = *(const float4*)(rp);
                *(float4*)&r_[4] = *(const float4*)(rp + 4);
                *(float4*)&r_[8] = *(const float4*)(rp + 8);
#pragma unroll
                for (int dx = 0; dx < ND; ++dx)
#pragma unroll
                    for (int p = 0; p < PX; ++p)
                        acc[s][dx][p] = fmaf(a_[p], r_[p + dx], acc[s][dx][p]);
            }
        }

        // ---- write prefetched regs to the other buffer (late write) ----
        if (rr + 1 < ROUNDS) {
#pragma unroll
            for (int i = 0; i < SIT; ++i)
                if (wr[i]) *(float4*)&s2[cur ^ 1][lofs[i]] = v[i];
        }
    }

    // ---- epilogue: mean over channels, write 27 planes of [B, 81, H, W] ----
    const float scale = 1.0f / (float)C_;
#pragma unroll
    for (int s = 0; s < GD; ++s)
#pragma unroll
        for (int dx = 0; dx < ND; ++dx) {
            float4 w4 = make_float4(acc[s][dx][0] * scale, acc[s][dx][1] * scale,
                                    acc[s][dx][2] * scale, acc[s][dx][3] * scale);
            *(float4*)(opb + (size_t)((g * GD + s) * ND + dx) * PLANE) = w4;
        }
}

extern "C" void kernel_launch(void* const* d_in, const int* in_sizes, int n_in,
                              void* d_out, int out_size, void* d_ws, size_t ws_size,
                              hipStream_t stream)
{
    const float* feat1 = (const float*)d_in[0];
    const float* feat2 = (const float*)d_in[1];
    float* out = (float*)d_out;

    dim3 grid((W_ / TW) * NG, H_ / TH, B_);   // 21 x 12 x 4 = 1008 blocks
    dim3 block(NTH);
    corr81_kernel<<<grid, block, 0, stream>>>(feat1, feat2, out);
}

// Round 2
// 440.534 us; speedup vs baseline: 2.1547x; 2.1547x over previous
//
#include <hip/hip_runtime.h>

namespace {
constexpr int D_  = 4;
constexpr int ND  = 9;     // 2D+1
constexpr int NK  = 81;
constexpr int B_  = 4, C_ = 64, H_ = 192, W_ = 448;

constexpr int TH  = 16;    // output rows per block
constexpr int TXN = 16;    // threads along x
constexpr int PX  = 4;     // pixels per thread along x
constexpr int TW  = TXN * PX;          // 64
constexpr int CCH = 8;                 // channels staged per round
constexpr int HC  = TW + 2 * D_;       // 72 halo cols
constexpr int HCP = 76;                // padded LDS row stride (76%32=12 -> uniform b128 banks)
constexpr int NTH = TH * TXN;          // 256
constexpr int ROUNDS = C_ / CCH;       // 8
constexpr int PLANE  = H_ * W_;        // 86016
}

__global__ __launch_bounds__(NTH, 4)
void corr81_kernel(const float* __restrict__ f1, const float* __restrict__ f2,
                   float* __restrict__ out)
{
    __shared__ float s2[CCH * TH * HCP];   // 8*16*76*4 = 38912 B -> 4 blocks/CU

    const int tid = threadIdx.x;
    const int tx  = tid & (TXN - 1);
    const int ty  = tid >> 4;

    const int bx    = blockIdx.x;
    const int tilex = bx / ND;         // 0..6
    const int g     = bx - tilex * ND; // dy index 0..8, fastest-varying -> L3 reuse

    const int x0 = tilex * TW;
    const int y0 = blockIdx.y * TH;
    const int b  = blockIdx.z;

    const int gx = x0 + tx * PX;
    const int gy = y0 + ty;

    // ---- staging geometry (round-invariant, computed once) ----
    // this thread stages feat2 row (y0 + g - D + ty), float4 chunk p=tx;
    // lanes tx<2 additionally stage chunks p=16,17 (x-halo tail)
    const int  yy  = y0 + g - D_ + ty;
    const bool okY = (yy >= 0) && (yy < H_);
    const int  yc  = yy < 0 ? 0 : (yy >= H_ ? H_ - 1 : yy);

    const int  xxM = x0 - 4 + 4 * tx;           // main chunk, 16B-aligned
    const bool okM = okY && (xxM >= 0);         // right edge always in-bounds for main
    const int  xcM = xxM < 0 ? 0 : xxM;

    const int  xxE = x0 + 60 + 4 * tx;          // extra chunk (only tx<2 uses it)
    const bool okE = okY && (xxE + 3 < W_);
    const int  xcE = okE ? xxE : 0;

    const size_t f2b = (size_t)(b * C_) * PLANE;
    const float* f2M = f2 + f2b + (size_t)yc * W_ + xcM;
    const float* f2E = f2 + f2b + (size_t)yc * W_ + xcE;

    float* const sM = s2 + ty * HCP + 4 * tx;
    float* const sE = s2 + ty * HCP + 64 + 4 * tx;
    const float* const sbase = s2 + ty * HCP + 4 * tx;   // compute read base (col 4*tx)

    const float* f1q = f1 + ((size_t)(b * C_) * H_ + gy) * W_ + gx;

    float acc[ND][PX];
#pragma unroll
    for (int dx = 0; dx < ND; ++dx)
#pragma unroll
        for (int p = 0; p < PX; ++p) acc[dx][p] = 0.f;

    for (int rr = 0; rr < ROUNDS; ++rr) {
        __syncthreads();   // protect previous round's LDS reads
        const size_t coff = (size_t)(rr * CCH) * PLANE;

        // ---- stage CCH channels: one f4 per (c) per thread + 2-lane halo tail ----
#pragma unroll
        for (int c = 0; c < CCH; ++c) {
            float4 t = make_float4(0.f, 0.f, 0.f, 0.f);
            if (okM) t = *(const float4*)(f2M + coff + (size_t)c * PLANE);
            *(float4*)(sM + c * (TH * HCP)) = t;
        }
        if (tx < 2) {
#pragma unroll
            for (int c = 0; c < CCH; ++c) {
                float4 t = make_float4(0.f, 0.f, 0.f, 0.f);
                if (okE) t = *(const float4*)(f2E + coff + (size_t)c * PLANE);
                *(float4*)(sE + c * (TH * HCP)) = t;
            }
        }
        __syncthreads();

        // ---- compute: 8 channels x 9 dx x 4 px ----
#pragma unroll
        for (int c = 0; c < CCH; ++c) {
            float4 af = *(const float4*)(f1q + coff + (size_t)c * PLANE);
            float a_[PX] = {af.x, af.y, af.z, af.w};
            const float* rp = sbase + c * (TH * HCP);
            float r_[12];
            *(float4*)&r_[0] = *(const float4*)(rp);
            *(float4*)&r_[4] = *(const float4*)(rp + 4);
            *(float4*)&r_[8] = *(const float4*)(rp + 8);
#pragma unroll
            for (int dx = 0; dx < ND; ++dx)
#pragma unroll
                for (int p = 0; p < PX; ++p)
                    acc[dx][p] = fmaf(a_[p], r_[p + dx], acc[dx][p]);
        }
    }

    // ---- epilogue: mean over channels, write planes g*9+dx of [B, 81, H, W] ----
    const float scale = 1.0f / (float)C_;
    float* const op = out + ((size_t)(b * NK) * H_ + gy) * W_ + gx;
#pragma unroll
    for (int dx = 0; dx < ND; ++dx) {
        float4 w4 = make_float4(acc[dx][0] * scale, acc[dx][1] * scale,
                                acc[dx][2] * scale, acc[dx][3] * scale);
        *(float4*)(op + (size_t)(g * ND + dx) * PLANE) = w4;
    }
}

extern "C" void kernel_launch(void* const* d_in, const int* in_sizes, int n_in,
                              void* d_out, int out_size, void* d_ws, size_t ws_size,
                              hipStream_t stream)
{
    const float* feat1 = (const float*)d_in[0];
    const float* feat2 = (const float*)d_in[1];
    float* out = (float*)d_out;

    dim3 grid((W_ / TW) * ND, H_ / TH, B_);   // 63 x 12 x 4 = 3024 blocks
    dim3 block(NTH);
    corr81_kernel<<<grid, block, 0, stream>>>(feat1, feat2, out);
}